// Round 17
// baseline (1569.789 us; speedup 1.0000x reference)
//
#include <hip/hip_runtime.h>
#include <hip/hip_fp16.h>

#define B_   32
#define S_   256
#define EMB_ 512
#define H_   1024
#define G4_  4096
#define NL_  5
#define NBLK 128

typedef _Float16 f16x8 __attribute__((ext_vector_type(8)));
typedef float f32x4 __attribute__((ext_vector_type(4)));
typedef unsigned long long ull;

__device__ inline ull ldq(const ull* p) {
  return __hip_atomic_load(p, __ATOMIC_RELAXED, __HIP_MEMORY_SCOPE_AGENT);
}
__device__ inline unsigned ldw(const unsigned* p) {
  return __hip_atomic_load(p, __ATOMIC_RELAXED, __HIP_MEMORY_SCOPE_AGENT);
}
__device__ inline void stw(unsigned* p, unsigned v) {
  __hip_atomic_store(p, v, __ATOMIC_RELAXED, __HIP_MEMORY_SCOPE_AGENT);
}
__device__ inline float sigm(float x) {
  return __builtin_amdgcn_rcpf(1.f + __expf(-x));
}
__device__ inline float ftanh(float x) {
  float e = __expf(2.f * x);
  return (e - 1.f) * __builtin_amdgcn_rcpf(e + 1.f);
}

// ---------------------------------------------------------------------------
// K0: transpose src [K][4096] -> dst [4096][K]. grid (128, K/32).
__global__ __launch_bounds__(256) void k_transposeK(const float* __restrict__ src,
                                                    float* __restrict__ dst, int K) {
  __shared__ float tile[32][33];
  int c0 = blockIdx.x * 32, k0 = blockIdx.y * 32;
  int tx = threadIdx.x & 31, ty = threadIdx.x >> 5;
#pragma unroll
  for (int i = 0; i < 4; ++i)
    tile[ty + 8 * i][tx] = src[(size_t)(k0 + ty + 8 * i) * G4_ + c0 + tx];
  __syncthreads();
#pragma unroll
  for (int i = 0; i < 4; ++i)
    dst[(size_t)(c0 + ty + 8 * i) * K + k0 + tx] = tile[tx][ty + 8 * i];
}

// ---------------------------------------------------------------------------
// K0b: U -> fp16 MFMA B-fragments, hi plane + lo*1024 plane. (proven math)
// Ubf[((ug*4 + ks)*8 + s8)*128 + plane*64 + l]: value U[k][gcol],
// k = ks*256 + s8*32 + (l>>4)*8 + j, n16=l&15, gcol=(n16&3)*1024+ug*4+(n16>>2).
// TOTAL SIZE 16 MiB — fully reserved.
__global__ __launch_bounds__(256) void k_prepU16(const float* __restrict__ Ut,
                                                 f16x8* __restrict__ Ubf) {
  int gid = blockIdx.x * 256 + threadIdx.x;
  int l = gid & 63;
  int bxws = gid >> 6;
  int n = l & 15, kgrp = l >> 4;
  int s = bxws & 7, bw = bxws >> 3;
  int w = bw & 3, bx = bw >> 2;
  int g = n & 3, ju = n >> 2;
  int gcol = g * 1024 + bx * 4 + ju;
  int kbase = w * 256 + s * 32 + kgrp * 8;
  const float4* f = (const float4*)(Ut + (size_t)gcol * H_ + kbase);
  float4 f0 = f[0], f1 = f[1];
  float v[8] = {f0.x, f0.y, f0.z, f0.w, f1.x, f1.y, f1.z, f1.w};
  f16x8 vh, vl;
#pragma unroll
  for (int j = 0; j < 8; ++j) {
    _Float16 hi = (_Float16)v[j];
    vh[j] = hi;
    vl[j] = (_Float16)((v[j] - (float)hi) * 1024.f);
  }
  Ubf[(size_t)bxws * 128 + l] = vh;
  Ubf[(size_t)bxws * 128 + 64 + l] = vl;
}

// ---------------------------------------------------------------------------
// K0c: W -> fp16 MFMA B-fragments (single plane). (proven)
__global__ __launch_bounds__(256) void k_prepW16(const float* __restrict__ Wt,
                                                 unsigned short* __restrict__ Wf16) {
  int gid = blockIdx.x * 256 + threadIdx.x;   // 262144 total
  int l = gid & 63, fi = gid >> 6;
  int kc = fi & 15, ug = fi >> 4;
  int n16 = l & 15, kgrp = l >> 4;
  int gcol = (n16 & 3) * 1024 + ug * 4 + (n16 >> 2);
  const float4* f = (const float4*)(Wt + (size_t)gcol * 512 + kc * 32 + kgrp * 8);
  float4 f0 = f[0], f1 = f[1];
  float v[8] = {f0.x, f0.y, f0.z, f0.w, f1.x, f1.y, f1.z, f1.w};
  union { unsigned short u[8]; uint4 q; } o;
#pragma unroll
  for (int j = 0; j < 8; ++j) o.u[j] = __half_as_ushort(__float2half_rn(v[j]));
  *(uint4*)(Wf16 + ((size_t)fi * 64 + l) * 8) = o.q;
}

// ---------------------------------------------------------------------------
// K0d: gather emb rows -> Xf16 [256 s][32 b][512 e] fp16. (proven)
__global__ __launch_bounds__(256) void k_prepX(const int* __restrict__ tokens,
                                               const float* __restrict__ emb,
                                               unsigned short* __restrict__ Xf16) {
  int gid = blockIdx.x * 256 + threadIdx.x;   // 524288 total
  int seg = gid & 63, row = gid >> 6;
  int s = row >> 5, b = row & 31;
  int tok = tokens[b * 256 + s];
  const float4* f = (const float4*)(emb + (size_t)tok * EMB_ + seg * 8);
  float4 f0 = f[0], f1 = f[1];
  float v[8] = {f0.x, f0.y, f0.z, f0.w, f1.x, f1.y, f1.z, f1.w};
  union { unsigned short u[8]; uint4 q; } o;
#pragma unroll
  for (int j = 0; j < 8; ++j) o.u[j] = __half_as_ushort(__float2half_rn(v[j]));
  *(uint4*)(Xf16 + (size_t)row * 512 + seg * 8) = o.q;
}

// ---------------------------------------------------------------------------
// K2: persistent steps v13 = r16 structure (2 barriers, parity double-buffer,
// early publish) with two fixes:
//  (a) packed sub-flags: block bx's 4 wave-flags live in ONE 16B line
//      flg[bx*4 + wave]; consumers poll 16 lines/wave (lanes use l&15), not 64.
//  (b) post-poll order: A ldq issued FIRST, xz MFMAs (operands pre-loaded into
//      regs before the poll) run while A loads are in flight.
// U-hi fp16 in LDS (64 KiB); U-lo*1024 from L2 each step pre-poll.
// h: fp16 pair-packed words at LLC; word idx ((m*128+kidx)*16+row)*4+(j>>1).
__global__ __launch_bounds__(512, 2) void k_steps13(
    const f16x8* __restrict__ Ubf,
    const unsigned short* __restrict__ Wf16,
    const unsigned short* __restrict__ Xf16,
    const float* __restrict__ bias,
    unsigned* __restrict__ T0, unsigned* __restrict__ T1,
    unsigned* __restrict__ flg) {
  __shared__ f16x8 UL[4096];        // 64 KiB hi plane: cg*2048 + ks*512 + s8*64 + l
  __shared__ float red[2][8192];    // 64 KiB: (w*4 + m2*2 + cg)*256 + l*4 + r
  __shared__ float zg[2][1056];     // 8.25 KiB: zb*33 + cg*16 + n16
  __shared__ float bias_s[32];

  const int tid = threadIdx.x;
  const int bx = blockIdx.x;
  const int l = tid & 63, w = tid >> 6;

  // --- stage U-hi into LDS once ---
#pragma unroll
  for (int i = 0; i < 8; ++i) {
    int flat = i * 512 + tid;
    int ll = flat & 63, s8 = (flat >> 6) & 7, ks = (flat >> 9) & 3;
    int cg = flat >> 11;
    size_t fi = (size_t)((bx * 2 + cg) * 4 + ks) * 8 + s8;
    UL[flat] = Ubf[fi * 128 + ll];           // hi plane
  }
  if (tid < 32) {
    int cg = tid >> 4, n16 = tid & 15;
    bias_s[tid] = bias[(n16 & 3) * 1024 + (bx * 2 + cg) * 4 + (n16 >> 2)];
  }

  // final-reduce mapping (r9-proven)
  const int e = tid & 255, m = tid >> 8;
  const int n16r = (e >> 2) & 15;
  const int zb = m * 16 + (e >> 6) * 4 + (e & 3);

  // gate mapping (tid<256): b=gb, unit gu (0..7)
  const int gb = tid & 31, gu = tid >> 5;
  const int widx = (((gb >> 4) * 128 + bx) * 16 + (gb & 15)) * 4 + (gu >> 1);
  const int zrd = gb * 33 + (gu >> 2) * 16 + (gu & 3) * 4;
  float creg = 0.f;

  const int ks_w = w >> 1;
  const int xrow0 = (l & 15) * 512 + (l >> 4) * 8;
  // packed sub-flags: block p's 4 flags at flg[p*4 .. p*4+3] (one 16B line).
  // wave w polls its 16 producers (blocks w*16 .. w*16+15), lane uses l&15.
  const ull* myflg = (const ull*)(flg + (size_t)(w * 16 + (l & 15)) * 4);

  __syncthreads();   // U staged

  for (int t = 0; t < S_; ++t) {
    const int par = t & 1;
    const ull* R64 = (const ull*)(par ? T0 : T1);   // h_{t-1}
    unsigned* WrT = par ? T1 : T0;                  // h_t

    // ---- pre-poll: U-lo frag reloads (L2-resident, no h dep) ----
    f16x8 ulo[4][2];
#pragma unroll
    for (int s = 0; s < 4; ++s)
#pragma unroll
      for (int cg = 0; cg < 2; ++cg)
        ulo[s][cg] = Ubf[((size_t)((bx * 2 + cg) * 4 + ks_w) * 8 +
                          (w & 1) * 4 + s) * 128 + 64 + l];

    // ---- pre-poll: X and W fragment loads into registers ----
    f16x8 xa[2][2], wb[2][2];
    {
      const unsigned short* Xt = Xf16 + (size_t)t * 16384;
#pragma unroll
      for (int c2 = 0; c2 < 2; ++c2) {
        int kc = w * 2 + c2;
        xa[c2][0] = *(const f16x8*)(Xt + xrow0 + kc * 32);
        xa[c2][1] = *(const f16x8*)(Xt + 8192 + xrow0 + kc * 32);
        wb[c2][0] = *(const f16x8*)(Wf16 + ((size_t)((bx * 2 + 0) * 16 + kc) * 64 + l) * 8);
        wb[c2][1] = *(const f16x8*)(Wf16 + ((size_t)((bx * 2 + 1) * 16 + kc) * 64 + l) * 8);
      }
    }

    f32x4 acc[2][2], accL[2][2];
#pragma unroll
    for (int cg = 0; cg < 2; ++cg)
#pragma unroll
      for (int m2 = 0; m2 < 2; ++m2) {
        acc[cg][m2] = (f32x4){0.f, 0.f, 0.f, 0.f};
        accL[cg][m2] = (f32x4){0.f, 0.f, 0.f, 0.f};
      }

    // ---- poll + A-load issue (A loads fly while xz MFMAs run below) ----
    union F { ull q[2]; f16x8 v; };
    F A[2][4];
    if (t > 0) {
      const unsigned tg = (unsigned)t;
      while (true) {
        ull q0 = ldq(myflg), q1 = ldq(myflg + 1);
        bool ok = ((unsigned)q0 >= tg) && ((unsigned)(q0 >> 32) >= tg) &&
                  ((unsigned)q1 >= tg) && ((unsigned)(q1 >> 32) >= tg);
        if (__all((int)ok)) break;
        __builtin_amdgcn_s_sleep(1);
      }
#pragma unroll
      for (int m2 = 0; m2 < 2; ++m2)
#pragma unroll
        for (int s = 0; s < 4; ++s) {
          int kidx = w * 16 + s * 4 + (l >> 4);
          int b64 = ((m2 * 128 + kidx) * 16 + (l & 15)) * 2;
          A[m2][s].q[0] = ldq(R64 + b64);
          A[m2][s].q[1] = ldq(R64 + b64 + 1);
        }
    }

    // ---- xz MFMAs (hide A-load latency) ----
#pragma unroll
    for (int c2 = 0; c2 < 2; ++c2) {
      acc[0][0] = __builtin_amdgcn_mfma_f32_16x16x32_f16(xa[c2][0], wb[c2][0], acc[0][0], 0, 0, 0);
      acc[0][1] = __builtin_amdgcn_mfma_f32_16x16x32_f16(xa[c2][1], wb[c2][0], acc[0][1], 0, 0, 0);
      acc[1][0] = __builtin_amdgcn_mfma_f32_16x16x32_f16(xa[c2][0], wb[c2][1], acc[1][0], 0, 0, 0);
      acc[1][1] = __builtin_amdgcn_mfma_f32_16x16x32_f16(xa[c2][1], wb[c2][1], acc[1][1], 0, 0, 0);
    }

    // ---- recurrence MFMAs ----
    if (t > 0) {
#pragma unroll
      for (int s = 0; s < 4; ++s) {
        int s8 = (w & 1) * 4 + s;
#pragma unroll
        for (int cg = 0; cg < 2; ++cg) {
          f16x8 uhf = UL[cg * 2048 + ks_w * 512 + s8 * 64 + l];
          acc[cg][0]  = __builtin_amdgcn_mfma_f32_16x16x32_f16(A[0][s].v, uhf, acc[cg][0], 0, 0, 0);
          acc[cg][1]  = __builtin_amdgcn_mfma_f32_16x16x32_f16(A[1][s].v, uhf, acc[cg][1], 0, 0, 0);
          accL[cg][0] = __builtin_amdgcn_mfma_f32_16x16x32_f16(A[0][s].v, ulo[s][cg], accL[cg][0], 0, 0, 0);
          accL[cg][1] = __builtin_amdgcn_mfma_f32_16x16x32_f16(A[1][s].v, ulo[s][cg], accL[cg][1], 0, 0, 0);
        }
      }
    }

    // fold lo-plane: z = acc + accL/1024
#pragma unroll
    for (int cg = 0; cg < 2; ++cg)
#pragma unroll
      for (int m2 = 0; m2 < 2; ++m2)
        acc[cg][m2] += accL[cg][m2] * 9.765625e-4f;

    // ---- single-pass reduction write: 8 disjoint 4KB slots ----
#pragma unroll
    for (int cg = 0; cg < 2; ++cg)
#pragma unroll
      for (int m2 = 0; m2 < 2; ++m2)
        *(f32x4*)(&red[par][(w * 4 + m2 * 2 + cg) * 256 + l * 4]) = acc[cg][m2];
    __syncthreads();                               // BAR1

    // ---- final reduce (all 512 threads) + bias -> zg (conflict-free) ----
    {
      float z0 = bias_s[n16r], z1 = bias_s[16 + n16r];
#pragma unroll
      for (int ww = 0; ww < 8; ++ww) {
        z0 += red[par][(ww * 4 + m * 2 + 0) * 256 + e];
        z1 += red[par][(ww * 4 + m * 2 + 1) * 256 + e];
      }
      zg[par][zb * 33 + n16r] = z0;
      zg[par][zb * 33 + 16 + n16r] = z1;
    }
    __syncthreads();                               // BAR2

    // ---- gates (tid<256); waves 4-7 run ahead into next step ----
    if (tid < 256) {
      float zi = zg[par][zrd + 0];
      float zf = zg[par][zrd + 1];
      float zc = zg[par][zrd + 2];
      float zo = zg[par][zrd + 3];
      float ig = sigm(zi);
      float fg = sigm(zf);
      float gg = ftanh(zc);
      float og = sigm(zo);
      creg = fg * creg + ig * gg;
      float hv = og * ftanh(creg);
      unsigned pk = (unsigned)__half_as_ushort(__float2half_rn(hv));
      unsigned other = (unsigned)__shfl_xor((int)pk, 32, 64);   // partner unit gu^1
      if ((gu & 1) == 0)
        stw(WrT + widx, (pk & 0xffffu) | (other << 16));
      // per-wave drain + early packed sub-flag publish
      asm volatile("s_waitcnt vmcnt(0)" ::: "memory");
      if ((tid & 63) == 0)
        stw(flg + (size_t)(bx * 4 + (tid >> 6)), (unsigned)(t + 1));
    }
    // NO trailing barrier: red/zg parity double-buffered (r16-proven).
  }
}

// ---------------------------------------------------------------------------
// K3: logits from pair-packed fp16 h (t=255 -> T1). grid 5, block 256. (proven)
__global__ __launch_bounds__(256) void k_head6(const unsigned* __restrict__ T,
                                               const float* __restrict__ Wd,
                                               const float* __restrict__ bd,
                                               float* __restrict__ out) {
  __shared__ float red[32 * 9];
  int lbl = blockIdx.x;
  int tid = threadIdx.x;
  int b = tid >> 3, ks = tid & 7;
  float acc = 0.f;
  for (int k = ks * 128; k < ks * 128 + 128; ++k) {
    int idx = (((b >> 4) * 128 + (k >> 3)) * 16 + (b & 15)) * 4 + ((k & 7) >> 1);
    unsigned wv = T[idx];
    unsigned short h16 = (unsigned short)((k & 1) ? (wv >> 16) : (wv & 0xffffu));
    acc += __half2float(__ushort_as_half(h16)) * Wd[k * NL_ + lbl];
  }
  red[b * 9 + ks] = acc;
  __syncthreads();
  if (tid < 32) {
    float s = bd[lbl];
#pragma unroll
    for (int i = 0; i < 8; ++i) s += red[tid * 9 + i];
    out[tid * NL_ + lbl] = s;
  }
}

// ---------------------------------------------------------------------------
extern "C" void kernel_launch(void* const* d_in, const int* in_sizes, int n_in,
                              void* d_out, int out_size, void* d_ws, size_t ws_size,
                              hipStream_t stream) {
  const int* tokens  = (const int*)d_in[0];
  const float* emb   = (const float*)d_in[1];
  const float* W     = (const float*)d_in[2];
  const float* U     = (const float*)d_in[3];
  const float* bias  = (const float*)d_in[4];
  const float* Wd    = (const float*)d_in[5];
  const float* bd    = (const float*)d_in[6];
  float* out = (float*)d_out;

  char* ws = (char*)d_ws;
  // Layout (≈58.9 MB; Ubf fully reserved at 16 MiB):
  //   Xf16 fp16 [256][32][512]  @ 0           (8 MiB)
  //   Wf16 fp16 frags           @ 8,388,608   (4 MiB)
  //   Ut fp32 (transient)       @ 16,777,216  (16 MiB)
  //   Wt fp32 (transient)       @ 33,554,432  (8 MiB)
  //   Ubf fp16 hi/lo frags      @ 41,943,040  (16 MiB) -> ends 58,720,256
  //   T0, T1 (64 KiB each)      @ 58,720,256
  //   flg (128 x 16 B packed)   @ 58,851,328  (zeroed each launch)
  unsigned short* Xf16 = (unsigned short*)ws;
  unsigned short* Wf16 = (unsigned short*)(ws + 8388608);
  float* Ut          = (float*)(ws + 16777216);
  float* Wt          = (float*)(ws + 33554432);
  f16x8* Ubf         = (f16x8*)(ws + 41943040);
  unsigned* T0       = (unsigned*)(ws + 58720256);
  unsigned* T1       = (unsigned*)(ws + 58785792);
  unsigned* flg      = (unsigned*)(ws + 58851328);

  hipMemsetAsync(flg, 0, 4096, stream);
  k_transposeK<<<dim3(128, 32), 256, 0, stream>>>(U, Ut, 1024);
  k_prepU16<<<2048, 256, 0, stream>>>(Ut, Ubf);
  k_transposeK<<<dim3(128, 16), 256, 0, stream>>>(W, Wt, 512);
  k_prepW16<<<1024, 256, 0, stream>>>(Wt, Wf16);
  k_prepX<<<2048, 256, 0, stream>>>(tokens, emb, Xf16);

  k_steps13<<<NBLK, 512, 0, stream>>>(Ubf, Wf16, Xf16, bias, T0, T1, flg);

  // t=255 (odd) wrote T1
  k_head6<<<NL_, 256, 0, stream>>>(T1, Wd, bd, out);
}

// Round 18
// 1039.138 us; speedup vs baseline: 1.5107x; 1.5107x over previous
//
#include <hip/hip_runtime.h>
#include <hip/hip_fp16.h>

#define B_   32
#define S_   256
#define EMB_ 512
#define H_   1024
#define G4_  4096
#define NL_  5
#define NBLK 128

typedef _Float16 f16x8 __attribute__((ext_vector_type(8)));
typedef float f32x4 __attribute__((ext_vector_type(4)));
typedef unsigned long long ull;

__device__ inline ull ldq(const ull* p) {
  return __hip_atomic_load(p, __ATOMIC_RELAXED, __HIP_MEMORY_SCOPE_AGENT);
}
__device__ inline unsigned ldw(const unsigned* p) {
  return __hip_atomic_load(p, __ATOMIC_RELAXED, __HIP_MEMORY_SCOPE_AGENT);
}
__device__ inline void stw(unsigned* p, unsigned v) {
  __hip_atomic_store(p, v, __ATOMIC_RELAXED, __HIP_MEMORY_SCOPE_AGENT);
}
__device__ inline float sigm(float x) {
  return __builtin_amdgcn_rcpf(1.f + __expf(-x));
}
__device__ inline float ftanh(float x) {
  float e = __expf(2.f * x);
  return (e - 1.f) * __builtin_amdgcn_rcpf(e + 1.f);
}

// ---------------------------------------------------------------------------
// K0: transpose src [K][4096] -> dst [4096][K]. grid (128, K/32).
__global__ __launch_bounds__(256) void k_transposeK(const float* __restrict__ src,
                                                    float* __restrict__ dst, int K) {
  __shared__ float tile[32][33];
  int c0 = blockIdx.x * 32, k0 = blockIdx.y * 32;
  int tx = threadIdx.x & 31, ty = threadIdx.x >> 5;
#pragma unroll
  for (int i = 0; i < 4; ++i)
    tile[ty + 8 * i][tx] = src[(size_t)(k0 + ty + 8 * i) * G4_ + c0 + tx];
  __syncthreads();
#pragma unroll
  for (int i = 0; i < 4; ++i)
    dst[(size_t)(c0 + ty + 8 * i) * K + k0 + tx] = tile[tx][ty + 8 * i];
}

// ---------------------------------------------------------------------------
// K0b: U -> fp16 MFMA B-fragments, hi plane + lo*1024 plane. (proven math)
// Ubf[((ug*4 + ks)*8 + s8)*128 + plane*64 + l]: value U[k][gcol],
// k = ks*256 + s8*32 + (l>>4)*8 + j, n16=l&15, gcol=(n16&3)*1024+ug*4+(n16>>2).
// TOTAL SIZE 16 MiB — fully reserved.
__global__ __launch_bounds__(256) void k_prepU16(const float* __restrict__ Ut,
                                                 f16x8* __restrict__ Ubf) {
  int gid = blockIdx.x * 256 + threadIdx.x;
  int l = gid & 63;
  int bxws = gid >> 6;
  int n = l & 15, kgrp = l >> 4;
  int s = bxws & 7, bw = bxws >> 3;
  int w = bw & 3, bx = bw >> 2;
  int g = n & 3, ju = n >> 2;
  int gcol = g * 1024 + bx * 4 + ju;
  int kbase = w * 256 + s * 32 + kgrp * 8;
  const float4* f = (const float4*)(Ut + (size_t)gcol * H_ + kbase);
  float4 f0 = f[0], f1 = f[1];
  float v[8] = {f0.x, f0.y, f0.z, f0.w, f1.x, f1.y, f1.z, f1.w};
  f16x8 vh, vl;
#pragma unroll
  for (int j = 0; j < 8; ++j) {
    _Float16 hi = (_Float16)v[j];
    vh[j] = hi;
    vl[j] = (_Float16)((v[j] - (float)hi) * 1024.f);
  }
  Ubf[(size_t)bxws * 128 + l] = vh;
  Ubf[(size_t)bxws * 128 + 64 + l] = vl;
}

// ---------------------------------------------------------------------------
// K0c: W -> fp16 MFMA B-fragments (single plane). (proven)
__global__ __launch_bounds__(256) void k_prepW16(const float* __restrict__ Wt,
                                                 unsigned short* __restrict__ Wf16) {
  int gid = blockIdx.x * 256 + threadIdx.x;   // 262144 total
  int l = gid & 63, fi = gid >> 6;
  int kc = fi & 15, ug = fi >> 4;
  int n16 = l & 15, kgrp = l >> 4;
  int gcol = (n16 & 3) * 1024 + ug * 4 + (n16 >> 2);
  const float4* f = (const float4*)(Wt + (size_t)gcol * 512 + kc * 32 + kgrp * 8);
  float4 f0 = f[0], f1 = f[1];
  float v[8] = {f0.x, f0.y, f0.z, f0.w, f1.x, f1.y, f1.z, f1.w};
  union { unsigned short u[8]; uint4 q; } o;
#pragma unroll
  for (int j = 0; j < 8; ++j) o.u[j] = __half_as_ushort(__float2half_rn(v[j]));
  *(uint4*)(Wf16 + ((size_t)fi * 64 + l) * 8) = o.q;
}

// ---------------------------------------------------------------------------
// K0d: gather emb rows -> Xf16 [256 s][32 b][512 e] fp16. (proven)
__global__ __launch_bounds__(256) void k_prepX(const int* __restrict__ tokens,
                                               const float* __restrict__ emb,
                                               unsigned short* __restrict__ Xf16) {
  int gid = blockIdx.x * 256 + threadIdx.x;   // 524288 total
  int seg = gid & 63, row = gid >> 6;
  int s = row >> 5, b = row & 31;
  int tok = tokens[b * 256 + s];
  const float4* f = (const float4*)(emb + (size_t)tok * EMB_ + seg * 8);
  float4 f0 = f[0], f1 = f[1];
  float v[8] = {f0.x, f0.y, f0.z, f0.w, f1.x, f1.y, f1.z, f1.w};
  union { unsigned short u[8]; uint4 q; } o;
#pragma unroll
  for (int j = 0; j < 8; ++j) o.u[j] = __half_as_ushort(__float2half_rn(v[j]));
  *(uint4*)(Xf16 + (size_t)row * 512 + seg * 8) = o.q;
}

// ---------------------------------------------------------------------------
// K2: persistent steps v12 (r16-proven best). grid 128 x 512 (8 waves).
// Block bx owns 8 units (32 gate cols, cg 0..1); wave w = K-slice
// [w*128,(w+1)*128). U-hi fp16 in LDS (64 KiB, staged once); U-lo*1024
// reloaded from L2 into regs each step BEFORE the poll (address-stable).
// Reduction: single-pass 8-slot red + zg staging, BOTH parity double-buffered
// -> only 2 barriers/step; conflict-free LDS throughout (r9-proven patterns).
// Gate waves (tid<256) store h, drain, publish sub-flags AFTER BAR2 while
// waves 4-7 run ahead into next step's prelude/poll (no trailing barrier).
// h: fp16 pair-packed words at LLC; word idx ((m*128+kidx)*16+row)*4+(j>>1).
// Sub-flags: 4/block, 64B apart; consumer wave w polls its 16 producers'
// 64 sub-flags, one lane each.
__global__ __launch_bounds__(512, 2) void k_steps12(
    const f16x8* __restrict__ Ubf,
    const unsigned short* __restrict__ Wf16,
    const unsigned short* __restrict__ Xf16,
    const float* __restrict__ bias,
    unsigned* __restrict__ T0, unsigned* __restrict__ T1,
    unsigned* __restrict__ flg) {
  __shared__ f16x8 UL[4096];        // 64 KiB hi plane: cg*2048 + ks*512 + s8*64 + l
  __shared__ float red[2][8192];    // 64 KiB: (w*4 + m2*2 + cg)*256 + l*4 + r
  __shared__ float zg[2][1056];     // 8.25 KiB: zb*33 + cg*16 + n16
  __shared__ float bias_s[32];

  const int tid = threadIdx.x;
  const int bx = blockIdx.x;
  const int l = tid & 63, w = tid >> 6;

  // --- stage U-hi into LDS once ---
#pragma unroll
  for (int i = 0; i < 8; ++i) {
    int flat = i * 512 + tid;
    int ll = flat & 63, s8 = (flat >> 6) & 7, ks = (flat >> 9) & 3;
    int cg = flat >> 11;
    size_t fi = (size_t)((bx * 2 + cg) * 4 + ks) * 8 + s8;
    UL[flat] = Ubf[fi * 128 + ll];           // hi plane
  }
  if (tid < 32) {
    int cg = tid >> 4, n16 = tid & 15;
    bias_s[tid] = bias[(n16 & 3) * 1024 + (bx * 2 + cg) * 4 + (n16 >> 2)];
  }

  // final-reduce mapping (r9-proven)
  const int e = tid & 255, m = tid >> 8;
  const int n16r = (e >> 2) & 15;
  const int zb = m * 16 + (e >> 6) * 4 + (e & 3);

  // gate mapping (tid<256): b=gb, unit gu (0..7)
  const int gb = tid & 31, gu = tid >> 5;
  const int widx = (((gb >> 4) * 128 + bx) * 16 + (gb & 15)) * 4 + (gu >> 1);
  const int zrd = gb * 33 + (gu >> 2) * 16 + (gu & 3) * 4;
  float creg = 0.f;

  const int ks_w = w >> 1;
  const int xrow0 = (l & 15) * 512 + (l >> 4) * 8;
  // sub-flag poll: lane l -> block w*16 + (l>>2), sub-flag l&3 (64B stride)
  const unsigned* myflg = flg + (size_t)((w * 16 + (l >> 2)) * 4 + (l & 3)) * 16;

  __syncthreads();   // U staged

  for (int t = 0; t < S_; ++t) {
    const int par = t & 1;
    const ull* R64 = (const ull*)(par ? T0 : T1);   // h_{t-1}
    unsigned* WrT = par ? T1 : T0;                  // h_t

    // ---- pre-poll: U-lo frag reloads (L2-resident, no h dep) ----
    f16x8 ulo[4][2];
#pragma unroll
    for (int s = 0; s < 4; ++s)
#pragma unroll
      for (int cg = 0; cg < 2; ++cg)
        ulo[s][cg] = Ubf[((size_t)((bx * 2 + cg) * 4 + ks_w) * 8 +
                          (w & 1) * 4 + s) * 128 + 64 + l];

    // ---- pre-poll: xz prelude acc = x_t @ W (fp16 MFMA) ----
    f32x4 acc[2][2], accL[2][2];
#pragma unroll
    for (int cg = 0; cg < 2; ++cg)
#pragma unroll
      for (int m2 = 0; m2 < 2; ++m2) {
        acc[cg][m2] = (f32x4){0.f, 0.f, 0.f, 0.f};
        accL[cg][m2] = (f32x4){0.f, 0.f, 0.f, 0.f};
      }
    {
      const unsigned short* Xt = Xf16 + (size_t)t * 16384;
#pragma unroll
      for (int c2 = 0; c2 < 2; ++c2) {
        int kc = w * 2 + c2;
        f16x8 xa0 = *(const f16x8*)(Xt + xrow0 + kc * 32);
        f16x8 xa1 = *(const f16x8*)(Xt + 8192 + xrow0 + kc * 32);
        f16x8 wb0 = *(const f16x8*)(Wf16 + ((size_t)((bx * 2 + 0) * 16 + kc) * 64 + l) * 8);
        f16x8 wb1 = *(const f16x8*)(Wf16 + ((size_t)((bx * 2 + 1) * 16 + kc) * 64 + l) * 8);
        acc[0][0] = __builtin_amdgcn_mfma_f32_16x16x32_f16(xa0, wb0, acc[0][0], 0, 0, 0);
        acc[0][1] = __builtin_amdgcn_mfma_f32_16x16x32_f16(xa1, wb0, acc[0][1], 0, 0, 0);
        acc[1][0] = __builtin_amdgcn_mfma_f32_16x16x32_f16(xa0, wb1, acc[1][0], 0, 0, 0);
        acc[1][1] = __builtin_amdgcn_mfma_f32_16x16x32_f16(xa1, wb1, acc[1][1], 0, 0, 0);
      }
    }

    // ---- recurrence: poll sub-flags, A loads, MFMA ----
    if (t > 0) {
      const unsigned tg = (unsigned)t;
      while (true) {
        unsigned v = ldw(myflg);
        if (__all((int)(v >= tg))) break;
        __builtin_amdgcn_s_sleep(1);
      }
      union F { ull q[2]; f16x8 v; };
      F A[2][4];
#pragma unroll
      for (int m2 = 0; m2 < 2; ++m2)
#pragma unroll
        for (int s = 0; s < 4; ++s) {
          int kidx = w * 16 + s * 4 + (l >> 4);
          int b64 = ((m2 * 128 + kidx) * 16 + (l & 15)) * 2;
          A[m2][s].q[0] = ldq(R64 + b64);
          A[m2][s].q[1] = ldq(R64 + b64 + 1);
        }
#pragma unroll
      for (int s = 0; s < 4; ++s) {
        int s8 = (w & 1) * 4 + s;
#pragma unroll
        for (int cg = 0; cg < 2; ++cg) {
          f16x8 uhf = UL[cg * 2048 + ks_w * 512 + s8 * 64 + l];
          acc[cg][0]  = __builtin_amdgcn_mfma_f32_16x16x32_f16(A[0][s].v, uhf, acc[cg][0], 0, 0, 0);
          acc[cg][1]  = __builtin_amdgcn_mfma_f32_16x16x32_f16(A[1][s].v, uhf, acc[cg][1], 0, 0, 0);
          accL[cg][0] = __builtin_amdgcn_mfma_f32_16x16x32_f16(A[0][s].v, ulo[s][cg], accL[cg][0], 0, 0, 0);
          accL[cg][1] = __builtin_amdgcn_mfma_f32_16x16x32_f16(A[1][s].v, ulo[s][cg], accL[cg][1], 0, 0, 0);
        }
      }
    }

    // fold lo-plane: z = acc + accL/1024
#pragma unroll
    for (int cg = 0; cg < 2; ++cg)
#pragma unroll
      for (int m2 = 0; m2 < 2; ++m2)
        acc[cg][m2] += accL[cg][m2] * 9.765625e-4f;

    // ---- single-pass reduction write: 8 disjoint 4KB slots ----
#pragma unroll
    for (int cg = 0; cg < 2; ++cg)
#pragma unroll
      for (int m2 = 0; m2 < 2; ++m2)
        *(f32x4*)(&red[par][(w * 4 + m2 * 2 + cg) * 256 + l * 4]) = acc[cg][m2];
    __syncthreads();                               // BAR1

    // ---- final reduce (all 512 threads) + bias -> zg (conflict-free) ----
    {
      float z0 = bias_s[n16r], z1 = bias_s[16 + n16r];
#pragma unroll
      for (int ww = 0; ww < 8; ++ww) {
        z0 += red[par][(ww * 4 + m * 2 + 0) * 256 + e];
        z1 += red[par][(ww * 4 + m * 2 + 1) * 256 + e];
      }
      zg[par][zb * 33 + n16r] = z0;
      zg[par][zb * 33 + 16 + n16r] = z1;
    }
    __syncthreads();                               // BAR2

    // ---- gates (tid<256); waves 4-7 run ahead into next step ----
    if (tid < 256) {
      float zi = zg[par][zrd + 0];
      float zf = zg[par][zrd + 1];
      float zc = zg[par][zrd + 2];
      float zo = zg[par][zrd + 3];
      float ig = sigm(zi);
      float fg = sigm(zf);
      float gg = ftanh(zc);
      float og = sigm(zo);
      creg = fg * creg + ig * gg;
      float hv = og * ftanh(creg);
      unsigned pk = (unsigned)__half_as_ushort(__float2half_rn(hv));
      unsigned other = (unsigned)__shfl_xor((int)pk, 32, 64);   // partner unit gu^1
      if ((gu & 1) == 0)
        stw(WrT + widx, (pk & 0xffffu) | (other << 16));
      // per-wave drain + early sub-flag publish
      asm volatile("s_waitcnt vmcnt(0)" ::: "memory");
      if ((tid & 63) == 0)
        stw(flg + (size_t)(bx * 4 + (tid >> 6)) * 16, (unsigned)(t + 1));
    }
    // NO trailing barrier: red/zg are parity double-buffered; WAR across two
    // steps is covered by BAR1/BAR2 of intervening steps.
  }
}

// ---------------------------------------------------------------------------
// K3: logits from pair-packed fp16 h (t=255 -> T1). grid 5, block 256. (proven)
__global__ __launch_bounds__(256) void k_head6(const unsigned* __restrict__ T,
                                               const float* __restrict__ Wd,
                                               const float* __restrict__ bd,
                                               float* __restrict__ out) {
  __shared__ float red[32 * 9];
  int lbl = blockIdx.x;
  int tid = threadIdx.x;
  int b = tid >> 3, ks = tid & 7;
  float acc = 0.f;
  for (int k = ks * 128; k < ks * 128 + 128; ++k) {
    int idx = (((b >> 4) * 128 + (k >> 3)) * 16 + (b & 15)) * 4 + ((k & 7) >> 1);
    unsigned wv = T[idx];
    unsigned short h16 = (unsigned short)((k & 1) ? (wv >> 16) : (wv & 0xffffu));
    acc += __half2float(__ushort_as_half(h16)) * Wd[k * NL_ + lbl];
  }
  red[b * 9 + ks] = acc;
  __syncthreads();
  if (tid < 32) {
    float s = bd[lbl];
#pragma unroll
    for (int i = 0; i < 8; ++i) s += red[tid * 9 + i];
    out[tid * NL_ + lbl] = s;
  }
}

// ---------------------------------------------------------------------------
extern "C" void kernel_launch(void* const* d_in, const int* in_sizes, int n_in,
                              void* d_out, int out_size, void* d_ws, size_t ws_size,
                              hipStream_t stream) {
  const int* tokens  = (const int*)d_in[0];
  const float* emb   = (const float*)d_in[1];
  const float* W     = (const float*)d_in[2];
  const float* U     = (const float*)d_in[3];
  const float* bias  = (const float*)d_in[4];
  const float* Wd    = (const float*)d_in[5];
  const float* bd    = (const float*)d_in[6];
  float* out = (float*)d_out;

  char* ws = (char*)d_ws;
  // Layout (≈58.9 MB; Ubf fully reserved at 16 MiB):
  //   Xf16 fp16 [256][32][512]  @ 0           (8 MiB)
  //   Wf16 fp16 frags           @ 8,388,608   (4 MiB)
  //   Ut fp32 (transient)       @ 16,777,216  (16 MiB)
  //   Wt fp32 (transient)       @ 33,554,432  (8 MiB)
  //   Ubf fp16 hi/lo frags      @ 41,943,040  (16 MiB) -> ends 58,720,256
  //   T0, T1 (64 KiB each)      @ 58,720,256
  //   flg (512 sub-flags x 64B) @ 58,851,328  (32 KiB, zeroed each launch)
  unsigned short* Xf16 = (unsigned short*)ws;
  unsigned short* Wf16 = (unsigned short*)(ws + 8388608);
  float* Ut          = (float*)(ws + 16777216);
  float* Wt          = (float*)(ws + 33554432);
  f16x8* Ubf         = (f16x8*)(ws + 41943040);
  unsigned* T0       = (unsigned*)(ws + 58720256);
  unsigned* T1       = (unsigned*)(ws + 58785792);
  unsigned* flg      = (unsigned*)(ws + 58851328);

  hipMemsetAsync(flg, 0, 32768, stream);
  k_transposeK<<<dim3(128, 32), 256, 0, stream>>>(U, Ut, 1024);
  k_prepU16<<<2048, 256, 0, stream>>>(Ut, Ubf);
  k_transposeK<<<dim3(128, 16), 256, 0, stream>>>(W, Wt, 512);
  k_prepW16<<<1024, 256, 0, stream>>>(Wt, Wf16);
  k_prepX<<<2048, 256, 0, stream>>>(tokens, emb, Xf16);

  k_steps12<<<NBLK, 512, 0, stream>>>(Ubf, Wf16, Xf16, bias, T0, T1, flg);

  // t=255 (odd) wrote T1
  k_head6<<<NL_, 256, 0, stream>>>(T1, Wd, bd, out);
}